// Round 7
// baseline (606.520 us; speedup 1.0000x reference)
//
#include <hip/hip_runtime.h>
#include <stdint.h>

typedef unsigned short u16;
typedef unsigned int u32;
typedef __attribute__((ext_vector_type(4))) float f32x4;
typedef __attribute__((ext_vector_type(16))) float f32x16;
typedef __attribute__((ext_vector_type(8))) short s16x8;
typedef __attribute__((ext_vector_type(4))) short s16x4;
typedef __attribute__((ext_vector_type(2))) unsigned int u32x2;
typedef __attribute__((ext_vector_type(4))) unsigned int u32x4;
typedef __attribute__((ext_vector_type(8))) int i32x8;

__device__ __forceinline__ u16 f2bf(float x){
  unsigned u = __builtin_bit_cast(unsigned, x);
  u += 0x7fffu + ((u >> 16) & 1u);
  return (u16)(u >> 16);
}
__device__ __forceinline__ float bf2f(u16 b){
  return __builtin_bit_cast(float, (unsigned)b << 16);
}
__device__ __forceinline__ u32 pk_fp8x4(float a, float b, float c, float d){
  int w = 0;
  w = __builtin_amdgcn_cvt_pk_fp8_f32(a, b, w, false);
  w = __builtin_amdgcn_cvt_pk_fp8_f32(c, d, w, true);
  return (u32)w;
}

// ---------------- device helpers ----------------

__device__ __forceinline__ void tcvtT_dev(const float* __restrict__ src, u16* __restrict__ dst,
                                          int K, int N, int bx, int by, char* smem){
  float (*t)[33] = (float (*)[33])smem;
  int tx = threadIdx.x & 31, ty = threadIdx.x >> 5;
  int n0 = bx * 32, k0 = by * 32;
  #pragma unroll
  for (int i = 0; i < 4; i++)
    t[ty + 8 * i][tx] = src[(size_t)(k0 + ty + 8 * i) * N + n0 + tx];
  __syncthreads();
  #pragma unroll
  for (int i = 0; i < 4; i++)
    dst[(size_t)(n0 + ty + 8 * i) * K + k0 + tx] = f2bf(t[tx][ty + 8 * i]);
}

__device__ __forceinline__ void bn_dev(const float* __restrict__ g, const float* __restrict__ b,
                                       const float* __restrict__ m, const float* __restrict__ v,
                                       const float* __restrict__ lin_b,
                                       float* __restrict__ s, float* __restrict__ bb,
                                       int n, int blk){
  int i = blk * 256 + threadIdx.x;
  if (i < n){
    float sc = g[i] * rsqrtf(v[i] + 1e-5f);
    s[i] = sc;
    bb[i] = (lin_b[i] - m[i]) * sc + b[i];
  }
}

// ---------------- prep0: w1 transpose-convert + bn1 ----------------
__global__ __launch_bounds__(256) void prep0_kernel(
    const float* __restrict__ enc_w1, u16* __restrict__ w1t,
    const float* __restrict__ g, const float* __restrict__ b,
    const float* __restrict__ m, const float* __restrict__ v,
    const float* __restrict__ lin_b, float* __restrict__ s1, float* __restrict__ bb1)
{
  __shared__ char smem[32 * 33 * 4 + 64];
  if (blockIdx.x < 512)
    tcvtT_dev(enc_w1, w1t, 1024, 512, blockIdx.x & 15, blockIdx.x >> 4, smem);
  else
    bn_dev(g, b, m, v, lin_b, s1, bb1, 512, blockIdx.x - 512);
}

// ---------------- fused enc1 GEMM + degree/fp8-convert + small preps ----------------
__global__ __launch_bounds__(256) void enc1_deg_kernel(
    const float* __restrict__ feature, const u16* __restrict__ w1t,
    u16* __restrict__ h1, const float* __restrict__ cs, const float* __restrict__ cb,
    const float* __restrict__ adj, unsigned char* __restrict__ adj8,
    float* __restrict__ dis,
    const float* __restrict__ enc_w2, u16* __restrict__ w2t,
    const float* __restrict__ gcn1_w, u16* __restrict__ g1t,
    const float* __restrict__ gcn2_w, u16* __restrict__ g2t,
    const float* __restrict__ bn2_g, const float* __restrict__ bn2_b,
    const float* __restrict__ bn2_m, const float* __restrict__ bn2_v,
    const float* __restrict__ enc_b2, float* __restrict__ s2, float* __restrict__ bb2)
{
  constexpr int BM = 128, BN = 256, BK = 64, WM = 2, WN = 2;
  constexpr int N = 512, K = 1024, NADJ = 16384;
  constexpr int WTM = BM / WM, WTN = BN / WN, FM = WTM / 16, FN = WTN / 16;
  constexpr int AIT = (BM * BK) / (256 * 4);
  constexpr int BIT = (BN * BK) / (256 * 8);

  __shared__ __align__(16) char smem[BM * BK * 2 + BN * BK * 2];

  if (blockIdx.x >= 16640){
    int p = blockIdx.x - 16640;
    if (p < 128)       tcvtT_dev(enc_w2, w2t, 512, 256, p & 7, p >> 3, smem);
    else if (p < 192){ int l = p - 128; tcvtT_dev(gcn1_w, g1t, 256, 256, l & 7, l >> 3, smem); }
    else if (p < 224){ int l = p - 192; tcvtT_dev(gcn2_w, g2t, 256, 128, l & 3, l >> 2, smem); }
    else               bn_dev(bn2_g, bn2_b, bn2_m, bn2_v, enc_b2, s2, bb2, 256, 0);
    return;
  }

  if (blockIdx.x >= 256){
    int row = blockIdx.x - 256;
    const float* rp = adj + (size_t)row * NADJ;
    unsigned char* wp = adj8 + (size_t)row * NADJ;
    float s = 0.f;
    #pragma unroll
    for (int it = 0; it < 4; ++it){
      const float* p = rp + it * 4096 + threadIdx.x * 16;
      f32x4 v[4];
      #pragma unroll
      for (int j = 0; j < 4; ++j) v[j] = *(const f32x4*)(p + 4 * j);
      u32x4 o;
      #pragma unroll
      for (int j = 0; j < 4; ++j){
        s += (v[j][0] + v[j][1]) + (v[j][2] + v[j][3]);
        o[j] = pk_fp8x4(v[j][0], v[j][1], v[j][2], v[j][3]);
      }
      *(u32x4*)(wp + it * 4096 + threadIdx.x * 16) = o;
    }
    #pragma unroll
    for (int d = 32; d > 0; d >>= 1) s += __shfl_down(s, d, 64);
    float* ps = (float*)smem;
    if ((threadIdx.x & 63) == 0) ps[threadIdx.x >> 6] = s;
    __syncthreads();
    if (threadIdx.x == 0) dis[row] = rsqrtf((ps[0] + ps[1]) + (ps[2] + ps[3]));
    return;
  }

  // ---- enc1 GEMM tile ----
  u16* As = (u16*)smem;
  u16* Bs = (u16*)(smem + BM * BK * 2);
  const int tid = threadIdx.x;
  const int lane = tid & 63;
  const int wid = tid >> 6;
  const int wr = wid / WN;
  const int wc = wid % WN;
  const int bm = (blockIdx.x & 127) * BM;
  const int bn = (blockIdx.x >> 7) * BN;

  f32x4 arf[AIT];
  s16x8 brb[BIT];

  auto load_tiles = [&](int k0){
    #pragma unroll
    for (int i = 0; i < AIT; i++){
      int e = (i * 256 + tid) * 4; int r = e / BK, c = e % BK;
      arf[i] = *(const f32x4*)(feature + (size_t)(bm + r) * K + k0 + c);
    }
    #pragma unroll
    for (int i = 0; i < BIT; i++){
      int e = (i * 256 + tid) * 8; int r = e / BK, c = e % BK;
      brb[i] = *(const s16x8*)(w1t + (size_t)(bn + r) * K + k0 + c);
    }
  };
  auto store_tiles = [&](){
    char* Ac = (char*)As; char* Bc = (char*)Bs;
    #pragma unroll
    for (int i = 0; i < AIT; i++){
      int e = (i * 256 + tid) * 4; int r = e / BK, c = e % BK;
      int off = ((r * BK + c) * 2) ^ ((r & 7) << 4);
      s16x4 o;
      o[0] = (short)f2bf(arf[i][0]); o[1] = (short)f2bf(arf[i][1]);
      o[2] = (short)f2bf(arf[i][2]); o[3] = (short)f2bf(arf[i][3]);
      *(s16x4*)(Ac + off) = o;
    }
    #pragma unroll
    for (int i = 0; i < BIT; i++){
      int e = (i * 256 + tid) * 8; int r = e / BK, c = e % BK;
      int off = ((r * BK + c) * 2) ^ ((r & 7) << 4);
      *(s16x8*)(Bc + off) = brb[i];
    }
  };

  f32x4 acc[FM][FN];
  #pragma unroll
  for (int m = 0; m < FM; m++)
    #pragma unroll
    for (int n = 0; n < FN; n++)
      acc[m][n] = (f32x4){0.f, 0.f, 0.f, 0.f};

  const int arow0 = wr * WTM + (lane & 15);
  const int brow0 = wc * WTN + (lane & 15);
  const int kof = (lane >> 4) * 8;

  load_tiles(0);
  for (int kt = 0; kt < K / BK; ++kt){
    __syncthreads();
    store_tiles();
    __syncthreads();
    if (kt + 1 < K / BK) load_tiles((kt + 1) * BK);
    const char* Ac = (const char*)As;
    const char* Bc = (const char*)Bs;
    #pragma unroll
    for (int ks = 0; ks < BK / 32; ++ks){
      s16x8 af[FM], bfr[FN];
      #pragma unroll
      for (int m = 0; m < FM; m++){
        int r = arow0 + m * 16;
        af[m] = *(const s16x8*)(Ac + (((r * BK + ks * 32 + kof) * 2) ^ ((r & 7) << 4)));
      }
      #pragma unroll
      for (int n = 0; n < FN; n++){
        int r = brow0 + n * 16;
        bfr[n] = *(const s16x8*)(Bc + (((r * BK + ks * 32 + kof) * 2) ^ ((r & 7) << 4)));
      }
      #pragma unroll
      for (int m = 0; m < FM; m++)
        #pragma unroll
        for (int n = 0; n < FN; n++)
          acc[m][n] = __builtin_amdgcn_mfma_f32_16x16x32_bf16(af[m], bfr[n], acc[m][n], 0, 0, 0);
    }
  }
  #pragma unroll
  for (int m = 0; m < FM; m++){
    #pragma unroll
    for (int n = 0; n < FN; n++){
      int col = bn + wc * WTN + n * 16 + (lane & 15);
      int row0 = bm + wr * WTM + m * 16 + (lane >> 4) * 4;
      #pragma unroll
      for (int r4 = 0; r4 < 4; r4++){
        float vv = fmaxf(acc[m][n][r4] * cs[col] + cb[col], 0.f);
        h1[(size_t)(row0 + r4) * N + col] = f2bf(vv);
      }
    }
  }
}

// ---------------- fused enc2 + gcn1-prescale (512 thr) ----------------
__global__ __launch_bounds__(512, 2)
void h2tT_kernel(const u16* __restrict__ h1, const u16* __restrict__ w2t,
                 const float* __restrict__ s2, const float* __restrict__ bb2,
                 const u16* __restrict__ g1t, const float* __restrict__ dis,
                 unsigned char* __restrict__ tT)
{
  constexpr int M = 16384, K1 = 512, K2 = 256, BK = 64;
  constexpr float SC = 256.f;

  __shared__ u16 As[64 * BK];
  __shared__ u16 Bs[256 * BK];
  __shared__ u16 H2s[64 * 256];

  const int tid = threadIdx.x;
  const int lane = tid & 63;
  const int wid = tid >> 6;
  const int wr = wid >> 2;
  const int wc = wid & 3;
  const int bm = blockIdx.x * 64;
  const int kof = (lane >> 4) * 8;

  {
    s16x8 arb, brb[4];
    auto load1 = [&](int k0){
      { int e = tid * 8; int r = e >> 6, c = e & 63;
        arb = *(const s16x8*)(h1 + (size_t)(bm + r) * K1 + k0 + c); }
      #pragma unroll
      for (int i = 0; i < 4; i++){
        int e = (i * 512 + tid) * 8; int r = e >> 6, c = e & 63;
        brb[i] = *(const s16x8*)(w2t + (size_t)r * K1 + k0 + c);
      }
    };
    auto store1 = [&](){
      char* Ac = (char*)As; char* Bc = (char*)Bs;
      { int e = tid * 8; int r = e >> 6, c = e & 63;
        *(s16x8*)(Ac + (((r * BK + c) * 2) ^ ((r & 7) << 4))) = arb; }
      #pragma unroll
      for (int i = 0; i < 4; i++){
        int e = (i * 512 + tid) * 8; int r = e >> 6, c = e & 63;
        *(s16x8*)(Bc + (((r * BK + c) * 2) ^ ((r & 7) << 4))) = brb[i];
      }
    };

    f32x4 acc[2][4];
    #pragma unroll
    for (int m = 0; m < 2; m++)
      #pragma unroll
      for (int n = 0; n < 4; n++)
        acc[m][n] = (f32x4){0.f, 0.f, 0.f, 0.f};

    load1(0);
    for (int kt = 0; kt < K1 / BK; ++kt){
      __syncthreads();
      store1();
      __syncthreads();
      if (kt + 1 < K1 / BK) load1((kt + 1) * BK);
      const char* Ac = (const char*)As;
      const char* Bc = (const char*)Bs;
      #pragma unroll
      for (int ks = 0; ks < 2; ++ks){
        s16x8 af[2], bfr[4];
        #pragma unroll
        for (int m = 0; m < 2; m++){
          int r = wr * 32 + m * 16 + (lane & 15);
          af[m] = *(const s16x8*)(Ac + (((r * BK + ks * 32 + kof) * 2) ^ ((r & 7) << 4)));
        }
        #pragma unroll
        for (int n = 0; n < 4; n++){
          int r = wc * 64 + n * 16 + (lane & 15);
          bfr[n] = *(const s16x8*)(Bc + (((r * BK + ks * 32 + kof) * 2) ^ ((r & 7) << 4)));
        }
        #pragma unroll
        for (int m = 0; m < 2; m++)
          #pragma unroll
          for (int n = 0; n < 4; n++)
            acc[m][n] = __builtin_amdgcn_mfma_f32_16x16x32_bf16(af[m], bfr[n], acc[m][n], 0, 0, 0);
      }
    }
    __syncthreads();
    char* Hc = (char*)H2s;
    #pragma unroll
    for (int m = 0; m < 2; m++){
      #pragma unroll
      for (int n = 0; n < 4; n++){
        int col = wc * 64 + n * 16 + (lane & 15);
        int row0 = wr * 32 + m * 16 + (lane >> 4) * 4;
        #pragma unroll
        for (int r4 = 0; r4 < 4; r4++){
          int row = row0 + r4;
          float vv = fmaxf(acc[m][n][r4] * s2[col] + bb2[col], 0.f);
          *(u16*)(Hc + (((row * 256 + col) * 2) ^ ((row & 7) << 4))) = f2bf(vv);
        }
      }
    }
  }

  {
    s16x8 brb[4];
    auto load2 = [&](int k0){
      #pragma unroll
      for (int i = 0; i < 4; i++){
        int e = (i * 512 + tid) * 8; int r = e >> 6, c = e & 63;
        brb[i] = *(const s16x8*)(g1t + (size_t)r * K2 + k0 + c);
      }
    };
    auto store2 = [&](){
      char* Bc = (char*)Bs;
      #pragma unroll
      for (int i = 0; i < 4; i++){
        int e = (i * 512 + tid) * 8; int r = e >> 6, c = e & 63;
        *(s16x8*)(Bc + (((r * BK + c) * 2) ^ ((r & 7) << 4))) = brb[i];
      }
    };

    f32x4 acc[2][4];
    #pragma unroll
    for (int m = 0; m < 2; m++)
      #pragma unroll
      for (int n = 0; n < 4; n++)
        acc[m][n] = (f32x4){0.f, 0.f, 0.f, 0.f};

    load2(0);
    for (int kt = 0; kt < K2 / BK; ++kt){
      __syncthreads();
      store2();
      __syncthreads();
      if (kt + 1 < K2 / BK) load2((kt + 1) * BK);
      const char* Hc = (const char*)H2s;
      const char* Bc = (const char*)Bs;
      #pragma unroll
      for (int ks = 0; ks < 2; ++ks){
        s16x8 af[2], bfr[4];
        #pragma unroll
        for (int m = 0; m < 2; m++){
          int r = wr * 32 + m * 16 + (lane & 15);
          af[m] = *(const s16x8*)(Hc + (((r * 256 + kt * 64 + ks * 32 + kof) * 2) ^ ((r & 7) << 4)));
        }
        #pragma unroll
        for (int n = 0; n < 4; n++){
          int r = wc * 64 + n * 16 + (lane & 15);
          bfr[n] = *(const s16x8*)(Bc + (((r * BK + ks * 32 + kof) * 2) ^ ((r & 7) << 4)));
        }
        #pragma unroll
        for (int m = 0; m < 2; m++)
          #pragma unroll
          for (int n = 0; n < 4; n++)
            acc[m][n] = __builtin_amdgcn_mfma_f32_16x16x32_bf16(af[m], bfr[n], acc[m][n], 0, 0, 0);
      }
    }
    #pragma unroll
    for (int m = 0; m < 2; m++){
      #pragma unroll
      for (int n = 0; n < 4; n++){
        int col = wc * 64 + n * 16 + (lane & 15);
        int row0 = bm + wr * 32 + m * 16 + (lane >> 4) * 4;
        float v0 = acc[m][n][0] * dis[row0 + 0] * SC;
        float v1 = acc[m][n][1] * dis[row0 + 1] * SC;
        float v2 = acc[m][n][2] * dis[row0 + 2] * SC;
        float v3 = acc[m][n][3] * dis[row0 + 3] * SC;
        *(u32*)(tT + (size_t)col * M + row0) = pk_fp8x4(v0, v1, v2, v3);
      }
    }
  }
}

// ---------------- MX fp8 GEMM, A via LDS (global_load_lds), B direct from L2/L3 ----------------
// P[z] = A8[M, kz:kz+Ksub] @ B8t[N=BN, kz:kz+Ksub]^T ; BM=128, 8 waves (2x4), split-K via z.
template<int BN>
__global__ __launch_bounds__(512, 4)
void gemm_mxd(const unsigned char* __restrict__ A8, const unsigned char* __restrict__ B8,
              float* __restrict__ P, int Ksub)
{
  constexpr int M = 16384, K = 16384, BM = 128, BK = 128;
  constexpr int AT = BM * BK;           // 16 KB
  constexpr int WTN = BN / 4;
  constexpr int FN = WTN / 32;          // 256->2, 128->1

  __shared__ __align__(16) char LDS[2 * AT];   // 32 KB

  const int tid = threadIdx.x;
  const int lane = tid & 63;
  const int wid = tid >> 6;
  const int wr = wid >> 2;   // 2 (M)
  const int wc = wid & 3;    // 4 (N)
  const int bm = blockIdx.x * BM;
  const int kz = blockIdx.z * Ksub;

  auto stageA = [&](int half, int k0){
    char* ab = LDS + half * AT;
    #pragma unroll
    for (int i = 0; i < 2; i++){
      int e = (i * 512 + tid) * 16;
      int r = e >> 7, c = e & 127;
      int cc = c ^ ((r & 7) << 4);
      const unsigned char* g = A8 + (size_t)(bm + r) * K + k0 + cc;
      __builtin_amdgcn_global_load_lds((const __attribute__((address_space(1))) unsigned int*)g,
          (__attribute__((address_space(3))) unsigned int*)(ab + e), 16, 0, 0);
    }
  };

  f32x16 acc[2][FN];
  #pragma unroll
  for (int m = 0; m < 2; m++)
    #pragma unroll
    for (int n = 0; n < FN; n++)
      #pragma unroll
      for (int i = 0; i < 16; i++)
        acc[m][n][i] = 0.f;

  const int nk = Ksub / BK;
  stageA(0, kz);
  for (int kt = 0; kt < nk; ++kt){
    __syncthreads();                                   // A tile kt drained; prev compute done
    if (kt + 1 < nk) stageA((kt + 1) & 1, kz + (kt + 1) * BK);
    const char* ab = LDS + (kt & 1) * AT;
    const int kb = kz + kt * BK;
    #pragma unroll
    for (int ks = 0; ks < 2; ks++){
      const int c0 = ks * 64 + (lane >> 5) * 32;
      i32x8 af[2];
      #pragma unroll
      for (int m = 0; m < 2; m++){
        int r = wr * 64 + m * 32 + (lane & 31);
        int sw = (r & 7) << 4;
        int o = r * BK + c0;
        u32x4 lo = *(const u32x4*)(ab + (o ^ sw));
        u32x4 hi = *(const u32x4*)(ab + ((o + 16) ^ sw));
        af[m][0]=lo[0];af[m][1]=lo[1];af[m][2]=lo[2];af[m][3]=lo[3];
        af[m][4]=hi[0];af[m][5]=hi[1];af[m][6]=hi[2];af[m][7]=hi[3];
      }
      #pragma unroll
      for (int n = 0; n < FN; n++){
        int rb = wc * WTN + n * 32 + (lane & 31);
        const unsigned char* gp = B8 + (size_t)rb * K + kb + c0;
        u32x4 lo = *(const u32x4*)gp;
        u32x4 hi = *(const u32x4*)(gp + 16);
        i32x8 bf;
        bf[0]=lo[0];bf[1]=lo[1];bf[2]=lo[2];bf[3]=lo[3];
        bf[4]=hi[0];bf[5]=hi[1];bf[6]=hi[2];bf[7]=hi[3];
        #pragma unroll
        for (int m = 0; m < 2; m++)
          acc[m][n] = __builtin_amdgcn_mfma_scale_f32_32x32x64_f8f6f4(
              af[m], bf, acc[m][n], 0, 0, 0, 0x7F7F7F7F, 0, 0x7F7F7F7F);
      }
    }
  }

  // C/D 32x32 layout: col = lane&31, row = (reg&3) + 8*(reg>>2) + 4*(lane>>5)
  float* Pz = P + (size_t)blockIdx.z * M * BN;
  #pragma unroll
  for (int m = 0; m < 2; m++){
    #pragma unroll
    for (int n = 0; n < FN; n++){
      int colg = wc * WTN + n * 32 + (lane & 31);
      int rbase = bm + wr * 64 + m * 32 + (lane >> 5) * 4;
      #pragma unroll
      for (int i = 0; i < 16; i++){
        int rowg = rbase + (i & 3) + 8 * (i >> 2);
        Pz[(size_t)rowg * BN + colg] = acc[m][n][i];
      }
    }
  }
}

// ---------------- fused reduce(4) + gcn2-prescale: t2T = fp8(SC*dis*(h3@g2w))^T ---------------
__global__ __launch_bounds__(256, 1)
void t2g_kernel(const float* __restrict__ part, const float* __restrict__ dis,
                const float* __restrict__ g1b, const u16* __restrict__ g2t,
                unsigned char* __restrict__ t2T)
{
  constexpr int M = 16384, H = 256, BK = 64;
  constexpr float SC = 256.f, SCI = 1.f / 256.f;
  const size_t MN = (size_t)M * H;

  __shared__ u16 As[64 * BK];
  __shared__ u16 Bs[128 * BK];

  const int tid = threadIdx.x;
  const int lane = tid & 63;
  const int wid = tid >> 6;
  const int wr = wid >> 1;
  const int wc = wid & 1;
  const int bm = blockIdx.x * 64;
  const int kof = (lane >> 4) * 8;

  f32x4 ar[4][4], gbr[4];
  float dsr[4];
  s16x8 brb[4];

  auto load_tiles = [&](int k0){
    #pragma unroll
    for (int i = 0; i < 4; i++){
      int e = (i * 256 + tid) * 4; int r = e >> 6, c = e & 63;
      size_t pi = (size_t)(bm + r) * H + k0 + c;
      #pragma unroll
      for (int s = 0; s < 4; s++)
        ar[s][i] = *(const f32x4*)(part + s * MN + pi);
      gbr[i] = *(const f32x4*)(g1b + k0 + c);
      dsr[i] = dis[bm + r];
    }
    #pragma unroll
    for (int i = 0; i < 4; i++){
      int e = (i * 256 + tid) * 8; int r = e >> 6, c = e & 63;
      brb[i] = *(const s16x8*)(g2t + (size_t)r * H + k0 + c);
    }
  };
  auto store_tiles = [&](){
    char* Ac = (char*)As; char* Bc = (char*)Bs;
    #pragma unroll
    for (int i = 0; i < 4; i++){
      int e = (i * 256 + tid) * 4; int r = e >> 6, c = e & 63;
      float dsc = dsr[i] * SCI;
      s16x4 o;
      #pragma unroll
      for (int j = 0; j < 4; j++){
        float vv = fmaxf(dsc * ((ar[0][i][j] + ar[1][i][j]) + (ar[2][i][j] + ar[3][i][j])) + gbr[i][j], 0.f);
        o[j] = (short)f2bf(vv);
      }
      *(s16x4*)(Ac + (((r * BK + c) * 2) ^ ((r & 7) << 4))) = o;
    }
    #pragma unroll
    for (int i = 0; i < 4; i++){
      int e = (i * 256 + tid) * 8; int r = e >> 6, c = e & 63;
      *(s16x8*)(Bc + (((r * BK + c) * 2) ^ ((r & 7) << 4))) = brb[i];
    }
  };

  f32x4 acc[2][4];
  #pragma unroll
  for (int m = 0; m < 2; m++)
    #pragma unroll
    for (int n = 0; n < 4; n++)
      acc[m][n] = (f32x4){0.f, 0.f, 0.f, 0.f};

  load_tiles(0);
  for (int kt = 0; kt < H / BK; ++kt){
    __syncthreads();
    store_tiles();
    __syncthreads();
    if (kt + 1 < H / BK) load_tiles((kt + 1) * BK);
    const char* Ac = (const char*)As;
    const char* Bc = (const char*)Bs;
    #pragma unroll
    for (int ks = 0; ks < 2; ++ks){
      s16x8 af[2], bfr[4];
      #pragma unroll
      for (int m = 0; m < 2; m++){
        int r = wr * 32 + m * 16 + (lane & 15);
        af[m] = *(const s16x8*)(Ac + (((r * BK + ks * 32 + kof) * 2) ^ ((r & 7) << 4)));
      }
      #pragma unroll
      for (int n = 0; n < 4; n++){
        int r = wc * 64 + n * 16 + (lane & 15);
        bfr[n] = *(const s16x8*)(Bc + (((r * BK + ks * 32 + kof) * 2) ^ ((r & 7) << 4)));
      }
      #pragma unroll
      for (int m = 0; m < 2; m++)
        #pragma unroll
        for (int n = 0; n < 4; n++)
          acc[m][n] = __builtin_amdgcn_mfma_f32_16x16x32_bf16(af[m], bfr[n], acc[m][n], 0, 0, 0);
    }
  }

  #pragma unroll
  for (int m = 0; m < 2; m++){
    #pragma unroll
    for (int n = 0; n < 4; n++){
      int col = wc * 64 + n * 16 + (lane & 15);
      int row0 = bm + wr * 32 + m * 16 + (lane >> 4) * 4;
      float v0 = acc[m][n][0] * dis[row0 + 0] * SC;
      float v1 = acc[m][n][1] * dis[row0 + 1] * SC;
      float v2 = acc[m][n][2] * dis[row0 + 2] * SC;
      float v3 = acc[m][n][3] * dis[row0 + 3] * SC;
      *(u32*)(t2T + (size_t)col * M + row0) = pk_fp8x4(v0, v1, v2, v3);
    }
  }
}

// ---------------- fused reduce(4) + classifier ----------------
__global__ __launch_bounds__(256) void cls2_kernel(const float* __restrict__ part,
                                                   const float* __restrict__ dis,
                                                   const float* __restrict__ g2b,
                                                   const float* __restrict__ w,
                                                   const float* __restrict__ b,
                                                   float* __restrict__ out)
{
  constexpr int M = 16384, G = 128;
  constexpr float SCI = 1.f / 256.f;
  const size_t MN = (size_t)M * G;
  __shared__ float ws_[G * 10];
  __shared__ float bs_[10];
  __shared__ float gb_[G];
  for (int i = threadIdx.x; i < G * 10; i += 256) ws_[i] = w[i];
  if (threadIdx.x < 10) bs_[threadIdx.x] = b[threadIdx.x];
  if (threadIdx.x < G) gb_[threadIdx.x] = g2b[threadIdx.x];
  __syncthreads();
  int row = blockIdx.x * 256 + threadIdx.x;
  const float* p0 = part + (size_t)row * G;
  float dr = dis[row] * SCI;
  float acc[10];
  #pragma unroll
  for (int c = 0; c < 10; c++) acc[c] = bs_[c];
  for (int k16 = 0; k16 < G; k16 += 16){
    f32x4 a[4];
    #pragma unroll
    for (int j = 0; j < 4; j++){
      a[j] = *(const f32x4*)(p0 + k16 + 4 * j);
      a[j] += *(const f32x4*)(p0 + MN + k16 + 4 * j);
      a[j] += *(const f32x4*)(p0 + 2 * MN + k16 + 4 * j);
      a[j] += *(const f32x4*)(p0 + 3 * MN + k16 + 4 * j);
    }
    #pragma unroll
    for (int j = 0; j < 16; j++){
      float h = fmaxf(dr * a[j >> 2][j & 3] + gb_[k16 + j], 0.f);
      #pragma unroll
      for (int c = 0; c < 10; c++) acc[c] = fmaf(h, ws_[(k16 + j) * 10 + c], acc[c]);
    }
  }
  #pragma unroll
  for (int c = 0; c < 10; c++){
    float sg = 1.f / (1.f + expf(-acc[c]));
    sg = fminf(fmaxf(sg, 1e-10f), 1.f - 1e-10f);
    out[(size_t)row * 10 + c] = sg;
  }
}

// ---------------- launcher ----------------

extern "C" void kernel_launch(void* const* d_in, const int* in_sizes, int n_in,
                              void* d_out, int out_size, void* d_ws, size_t ws_size,
                              hipStream_t stream)
{
  (void)in_sizes; (void)n_in; (void)out_size; (void)ws_size;
  const float* feature = (const float*)d_in[0];
  const float* adj     = (const float*)d_in[1];
  const float* enc_w1  = (const float*)d_in[2];
  const float* enc_b1  = (const float*)d_in[3];
  const float* bn1_g   = (const float*)d_in[4];
  const float* bn1_b   = (const float*)d_in[5];
  const float* bn1_m   = (const float*)d_in[6];
  const float* bn1_v   = (const float*)d_in[7];
  const float* enc_w2  = (const float*)d_in[8];
  const float* enc_b2  = (const float*)d_in[9];
  const float* bn2_g   = (const float*)d_in[10];
  const float* bn2_b   = (const float*)d_in[11];
  const float* bn2_m   = (const float*)d_in[12];
  const float* bn2_v   = (const float*)d_in[13];
  const float* gcn1_w  = (const float*)d_in[14];
  const float* gcn1_b  = (const float*)d_in[15];
  const float* gcn2_w  = (const float*)d_in[16];
  const float* gcn2_b  = (const float*)d_in[17];
  const float* cls_w   = (const float*)d_in[18];
  const float* cls_b   = (const float*)d_in[19];
  float* out = (float*)d_out;

  const int NN = 16384, F = 1024, H1 = 512, E = 256, H = 256, G = 128;

  char* ws = (char*)d_ws;
  size_t off = 0;
  auto alloc = [&](size_t bytes) -> char* {
    char* p = ws + off; off += (bytes + 255) & ~(size_t)255; return p;
  };
  float* dis = (float*)alloc((size_t)NN * 4);
  float* s1  = (float*)alloc((size_t)H1 * 4);
  float* bb1 = (float*)alloc((size_t)H1 * 4);
  float* s2  = (float*)alloc((size_t)E * 4);
  float* bb2 = (float*)alloc((size_t)E * 4);
  u16* w1t = (u16*)alloc((size_t)H1 * F * 2);
  u16* w2t = (u16*)alloc((size_t)E * H1 * 2);
  u16* g1t = (u16*)alloc((size_t)H * E * 2);
  u16* g2t = (u16*)alloc((size_t)G * H * 2);
  u16* h1  = (u16*)alloc((size_t)NN * H1 * 2);
  unsigned char* tT  = (unsigned char*)alloc((size_t)E * NN);
  unsigned char* t2T = (unsigned char*)alloc((size_t)G * NN);
  float* part = (float*)alloc((size_t)4 * NN * H * 4);
  unsigned char* adj8 = (unsigned char*)alloc((size_t)NN * NN);

  // 1) w1 transpose-convert + bn1 fold
  prep0_kernel<<<514, 256, 0, stream>>>(enc_w1, w1t, bn1_g, bn1_b, bn1_m, bn1_v, enc_b1, s1, bb1);

  // 2) fused: enc1 GEMM + degree/fp8 convert + w2t/g1t/g2t/bn2 preps
  enc1_deg_kernel<<<256 + NN + 225, 256, 0, stream>>>(
      feature, w1t, h1, s1, bb1, adj, adj8, dis,
      enc_w2, w2t, gcn1_w, g1t, gcn2_w, g2t,
      bn2_g, bn2_b, bn2_m, bn2_v, enc_b2, s2, bb2);

  // 3) fused enc2 + gcn1 prescale -> tT (fp8, transposed)
  h2tT_kernel<<<NN / 64, 512, 0, stream>>>(h1, w2t, s2, bb2, g1t, dis, tT);

  // 4) part[z] = adj8 @ tT (split-K 4, B direct from cache, 2 blocks/CU)
  gemm_mxd<256><<<dim3(NN/128, 1, 4), 512, 0, stream>>>(adj8, tT, part, NN/4);

  // 5) fused reduce(4) + gcn2 prescale -> t2T (fp8, transposed)
  t2g_kernel<<<NN / 64, 256, 0, stream>>>(part, dis, gcn1_b, g2t, t2T);

  // 6) part[z] = adj8 @ t2T (split-K 4)
  gemm_mxd<128><<<dim3(NN/128, 1, 4), 512, 0, stream>>>(adj8, t2T, part, NN/4);

  // 7) fused reduce(4) + classifier
  cls2_kernel<<<NN / 256, 256, 0, stream>>>(part, dis, gcn2_b, cls_w, cls_b, out);
}

// Round 8
// 471.463 us; speedup vs baseline: 1.2865x; 1.2865x over previous
//
#include <hip/hip_runtime.h>
#include <stdint.h>

typedef unsigned short u16;
typedef unsigned int u32;
typedef __attribute__((ext_vector_type(4))) float f32x4;
typedef __attribute__((ext_vector_type(16))) float f32x16;
typedef __attribute__((ext_vector_type(8))) short s16x8;
typedef __attribute__((ext_vector_type(4))) short s16x4;
typedef __attribute__((ext_vector_type(2))) unsigned int u32x2;
typedef __attribute__((ext_vector_type(4))) unsigned int u32x4;
typedef __attribute__((ext_vector_type(8))) int i32x8;

__device__ __forceinline__ u16 f2bf(float x){
  unsigned u = __builtin_bit_cast(unsigned, x);
  u += 0x7fffu + ((u >> 16) & 1u);
  return (u16)(u >> 16);
}
__device__ __forceinline__ float bf2f(u16 b){
  return __builtin_bit_cast(float, (unsigned)b << 16);
}
__device__ __forceinline__ u32 pk_fp8x4(float a, float b, float c, float d){
  int w = 0;
  w = __builtin_amdgcn_cvt_pk_fp8_f32(a, b, w, false);
  w = __builtin_amdgcn_cvt_pk_fp8_f32(c, d, w, true);
  return (u32)w;
}

// ---------------- device helpers ----------------

__device__ __forceinline__ void tcvtT_dev(const float* __restrict__ src, u16* __restrict__ dst,
                                          int K, int N, int bx, int by, char* smem){
  float (*t)[33] = (float (*)[33])smem;
  int tx = threadIdx.x & 31, ty = threadIdx.x >> 5;
  int n0 = bx * 32, k0 = by * 32;
  #pragma unroll
  for (int i = 0; i < 4; i++)
    t[ty + 8 * i][tx] = src[(size_t)(k0 + ty + 8 * i) * N + n0 + tx];
  __syncthreads();
  #pragma unroll
  for (int i = 0; i < 4; i++)
    dst[(size_t)(n0 + ty + 8 * i) * K + k0 + tx] = f2bf(t[tx][ty + 8 * i]);
}

__device__ __forceinline__ void bn_dev(const float* __restrict__ g, const float* __restrict__ b,
                                       const float* __restrict__ m, const float* __restrict__ v,
                                       const float* __restrict__ lin_b,
                                       float* __restrict__ s, float* __restrict__ bb,
                                       int n, int blk){
  int i = blk * 256 + threadIdx.x;
  if (i < n){
    float sc = g[i] * rsqrtf(v[i] + 1e-5f);
    s[i] = sc;
    bb[i] = (lin_b[i] - m[i]) * sc + b[i];
  }
}

// ---------------- prep0: w1 transpose-convert + bn1 ----------------
__global__ __launch_bounds__(256) void prep0_kernel(
    const float* __restrict__ enc_w1, u16* __restrict__ w1t,
    const float* __restrict__ g, const float* __restrict__ b,
    const float* __restrict__ m, const float* __restrict__ v,
    const float* __restrict__ lin_b, float* __restrict__ s1, float* __restrict__ bb1)
{
  __shared__ char smem[32 * 33 * 4 + 64];
  if (blockIdx.x < 512)
    tcvtT_dev(enc_w1, w1t, 1024, 512, blockIdx.x & 15, blockIdx.x >> 4, smem);
  else
    bn_dev(g, b, m, v, lin_b, s1, bb1, 512, blockIdx.x - 512);
}

// ---------------- fused enc1 GEMM + degree/fp8-convert + small preps ----------------
__global__ __launch_bounds__(256) void enc1_deg_kernel(
    const float* __restrict__ feature, const u16* __restrict__ w1t,
    u16* __restrict__ h1, const float* __restrict__ cs, const float* __restrict__ cb,
    const float* __restrict__ adj, unsigned char* __restrict__ adj8,
    float* __restrict__ dis,
    const float* __restrict__ enc_w2, u16* __restrict__ w2t,
    const float* __restrict__ gcn1_w, u16* __restrict__ g1t,
    const float* __restrict__ gcn2_w, u16* __restrict__ g2t,
    const float* __restrict__ bn2_g, const float* __restrict__ bn2_b,
    const float* __restrict__ bn2_m, const float* __restrict__ bn2_v,
    const float* __restrict__ enc_b2, float* __restrict__ s2, float* __restrict__ bb2)
{
  constexpr int BM = 128, BN = 256, BK = 64, WM = 2, WN = 2;
  constexpr int N = 512, K = 1024, NADJ = 16384;
  constexpr int WTM = BM / WM, WTN = BN / WN, FM = WTM / 16, FN = WTN / 16;
  constexpr int AIT = (BM * BK) / (256 * 4);
  constexpr int BIT = (BN * BK) / (256 * 8);

  __shared__ __align__(16) char smem[BM * BK * 2 + BN * BK * 2];

  if (blockIdx.x >= 16640){
    int p = blockIdx.x - 16640;
    if (p < 128)       tcvtT_dev(enc_w2, w2t, 512, 256, p & 7, p >> 3, smem);
    else if (p < 192){ int l = p - 128; tcvtT_dev(gcn1_w, g1t, 256, 256, l & 7, l >> 3, smem); }
    else if (p < 224){ int l = p - 192; tcvtT_dev(gcn2_w, g2t, 256, 128, l & 3, l >> 2, smem); }
    else               bn_dev(bn2_g, bn2_b, bn2_m, bn2_v, enc_b2, s2, bb2, 256, 0);
    return;
  }

  if (blockIdx.x >= 256){
    int row = blockIdx.x - 256;
    const float* rp = adj + (size_t)row * NADJ;
    unsigned char* wp = adj8 + (size_t)row * NADJ;
    float s = 0.f;
    #pragma unroll
    for (int it = 0; it < 4; ++it){
      const float* p = rp + it * 4096 + threadIdx.x * 16;
      f32x4 v[4];
      #pragma unroll
      for (int j = 0; j < 4; ++j) v[j] = *(const f32x4*)(p + 4 * j);
      u32x4 o;
      #pragma unroll
      for (int j = 0; j < 4; ++j){
        s += (v[j][0] + v[j][1]) + (v[j][2] + v[j][3]);
        o[j] = pk_fp8x4(v[j][0], v[j][1], v[j][2], v[j][3]);
      }
      *(u32x4*)(wp + it * 4096 + threadIdx.x * 16) = o;
    }
    #pragma unroll
    for (int d = 32; d > 0; d >>= 1) s += __shfl_down(s, d, 64);
    float* ps = (float*)smem;
    if ((threadIdx.x & 63) == 0) ps[threadIdx.x >> 6] = s;
    __syncthreads();
    if (threadIdx.x == 0) dis[row] = rsqrtf((ps[0] + ps[1]) + (ps[2] + ps[3]));
    return;
  }

  // ---- enc1 GEMM tile ----
  u16* As = (u16*)smem;
  u16* Bs = (u16*)(smem + BM * BK * 2);
  const int tid = threadIdx.x;
  const int lane = tid & 63;
  const int wid = tid >> 6;
  const int wr = wid / WN;
  const int wc = wid % WN;
  const int bm = (blockIdx.x & 127) * BM;
  const int bn = (blockIdx.x >> 7) * BN;

  f32x4 arf[AIT];
  s16x8 brb[BIT];

  auto load_tiles = [&](int k0){
    #pragma unroll
    for (int i = 0; i < AIT; i++){
      int e = (i * 256 + tid) * 4; int r = e / BK, c = e % BK;
      arf[i] = *(const f32x4*)(feature + (size_t)(bm + r) * K + k0 + c);
    }
    #pragma unroll
    for (int i = 0; i < BIT; i++){
      int e = (i * 256 + tid) * 8; int r = e / BK, c = e % BK;
      brb[i] = *(const s16x8*)(w1t + (size_t)(bn + r) * K + k0 + c);
    }
  };
  auto store_tiles = [&](){
    char* Ac = (char*)As; char* Bc = (char*)Bs;
    #pragma unroll
    for (int i = 0; i < AIT; i++){
      int e = (i * 256 + tid) * 4; int r = e / BK, c = e % BK;
      int off = ((r * BK + c) * 2) ^ ((r & 7) << 4);
      s16x4 o;
      o[0] = (short)f2bf(arf[i][0]); o[1] = (short)f2bf(arf[i][1]);
      o[2] = (short)f2bf(arf[i][2]); o[3] = (short)f2bf(arf[i][3]);
      *(s16x4*)(Ac + off) = o;
    }
    #pragma unroll
    for (int i = 0; i < BIT; i++){
      int e = (i * 256 + tid) * 8; int r = e / BK, c = e % BK;
      int off = ((r * BK + c) * 2) ^ ((r & 7) << 4);
      *(s16x8*)(Bc + off) = brb[i];
    }
  };

  f32x4 acc[FM][FN];
  #pragma unroll
  for (int m = 0; m < FM; m++)
    #pragma unroll
    for (int n = 0; n < FN; n++)
      acc[m][n] = (f32x4){0.f, 0.f, 0.f, 0.f};

  const int arow0 = wr * WTM + (lane & 15);
  const int brow0 = wc * WTN + (lane & 15);
  const int kof = (lane >> 4) * 8;

  load_tiles(0);
  for (int kt = 0; kt < K / BK; ++kt){
    __syncthreads();
    store_tiles();
    __syncthreads();
    if (kt + 1 < K / BK) load_tiles((kt + 1) * BK);
    const char* Ac = (const char*)As;
    const char* Bc = (const char*)Bs;
    #pragma unroll
    for (int ks = 0; ks < BK / 32; ++ks){
      s16x8 af[FM], bfr[FN];
      #pragma unroll
      for (int m = 0; m < FM; m++){
        int r = arow0 + m * 16;
        af[m] = *(const s16x8*)(Ac + (((r * BK + ks * 32 + kof) * 2) ^ ((r & 7) << 4)));
      }
      #pragma unroll
      for (int n = 0; n < FN; n++){
        int r = brow0 + n * 16;
        bfr[n] = *(const s16x8*)(Bc + (((r * BK + ks * 32 + kof) * 2) ^ ((r & 7) << 4)));
      }
      #pragma unroll
      for (int m = 0; m < FM; m++)
        #pragma unroll
        for (int n = 0; n < FN; n++)
          acc[m][n] = __builtin_amdgcn_mfma_f32_16x16x32_bf16(af[m], bfr[n], acc[m][n], 0, 0, 0);
    }
  }
  #pragma unroll
  for (int m = 0; m < FM; m++){
    #pragma unroll
    for (int n = 0; n < FN; n++){
      int col = bn + wc * WTN + n * 16 + (lane & 15);
      int row0 = bm + wr * WTM + m * 16 + (lane >> 4) * 4;
      #pragma unroll
      for (int r4 = 0; r4 < 4; r4++){
        float vv = fmaxf(acc[m][n][r4] * cs[col] + cb[col], 0.f);
        h1[(size_t)(row0 + r4) * N + col] = f2bf(vv);
      }
    }
  }
}

// ---------------- fused enc2 + gcn1-prescale (512 thr, BK=128) ----------------
__global__ __launch_bounds__(512, 1)
void h2tT_kernel(const u16* __restrict__ h1, const u16* __restrict__ w2t,
                 const float* __restrict__ s2, const float* __restrict__ bb2,
                 const u16* __restrict__ g1t, const float* __restrict__ dis,
                 unsigned char* __restrict__ tT)
{
  constexpr int M = 16384, K1 = 512, K2 = 256, BK = 128;
  constexpr float SC = 256.f;

  __shared__ u16 As[64 * BK];     // 16 KB
  __shared__ u16 Bs[256 * BK];    // 64 KB
  __shared__ u16 H2s[64 * 256];   // 32 KB

  const int tid = threadIdx.x;
  const int lane = tid & 63;
  const int wid = tid >> 6;
  const int wr = wid >> 2;
  const int wc = wid & 3;
  const int bm = blockIdx.x * 64;
  const int kof = (lane >> 4) * 8;

  // ---- phase 1: H2s = relu(bn2(h1[bm:bm+64][:] @ w2)) ----
  {
    s16x8 arb[2], brb[8];
    auto load1 = [&](int k0){
      #pragma unroll
      for (int i = 0; i < 2; i++){
        int e = (i * 512 + tid) * 8; int r = e >> 7, c = e & 127;
        arb[i] = *(const s16x8*)(h1 + (size_t)(bm + r) * K1 + k0 + c);
      }
      #pragma unroll
      for (int i = 0; i < 8; i++){
        int e = (i * 512 + tid) * 8; int r = e >> 7, c = e & 127;
        brb[i] = *(const s16x8*)(w2t + (size_t)r * K1 + k0 + c);
      }
    };
    auto store1 = [&](){
      char* Ac = (char*)As; char* Bc = (char*)Bs;
      #pragma unroll
      for (int i = 0; i < 2; i++){
        int e = (i * 512 + tid) * 8; int r = e >> 7, c = e & 127;
        *(s16x8*)(Ac + (((r * BK + c) * 2) ^ ((r & 7) << 4))) = arb[i];
      }
      #pragma unroll
      for (int i = 0; i < 8; i++){
        int e = (i * 512 + tid) * 8; int r = e >> 7, c = e & 127;
        *(s16x8*)(Bc + (((r * BK + c) * 2) ^ ((r & 7) << 4))) = brb[i];
      }
    };

    f32x4 acc[2][4];
    #pragma unroll
    for (int m = 0; m < 2; m++)
      #pragma unroll
      for (int n = 0; n < 4; n++)
        acc[m][n] = (f32x4){0.f, 0.f, 0.f, 0.f};

    load1(0);
    for (int kt = 0; kt < K1 / BK; ++kt){
      __syncthreads();
      store1();
      __syncthreads();
      if (kt + 1 < K1 / BK) load1((kt + 1) * BK);
      const char* Ac = (const char*)As;
      const char* Bc = (const char*)Bs;
      #pragma unroll
      for (int ks = 0; ks < 4; ++ks){
        s16x8 af[2], bfr[4];
        #pragma unroll
        for (int m = 0; m < 2; m++){
          int r = wr * 32 + m * 16 + (lane & 15);
          af[m] = *(const s16x8*)(Ac + (((r * BK + ks * 32 + kof) * 2) ^ ((r & 7) << 4)));
        }
        #pragma unroll
        for (int n = 0; n < 4; n++){
          int r = wc * 64 + n * 16 + (lane & 15);
          bfr[n] = *(const s16x8*)(Bc + (((r * BK + ks * 32 + kof) * 2) ^ ((r & 7) << 4)));
        }
        #pragma unroll
        for (int m = 0; m < 2; m++)
          #pragma unroll
          for (int n = 0; n < 4; n++)
            acc[m][n] = __builtin_amdgcn_mfma_f32_16x16x32_bf16(af[m], bfr[n], acc[m][n], 0, 0, 0);
      }
    }
    __syncthreads();
    char* Hc = (char*)H2s;
    #pragma unroll
    for (int m = 0; m < 2; m++){
      #pragma unroll
      for (int n = 0; n < 4; n++){
        int col = wc * 64 + n * 16 + (lane & 15);
        int row0 = wr * 32 + m * 16 + (lane >> 4) * 4;
        #pragma unroll
        for (int r4 = 0; r4 < 4; r4++){
          int row = row0 + r4;
          float vv = fmaxf(acc[m][n][r4] * s2[col] + bb2[col], 0.f);
          *(u16*)(Hc + (((row * 256 + col) * 2) ^ ((row & 7) << 4))) = f2bf(vv);
        }
      }
    }
  }

  // ---- phase 2: tT = fp8(SC * dis * (H2s @ g1w))^T ----
  {
    s16x8 brb[8];
    auto load2 = [&](int k0){
      #pragma unroll
      for (int i = 0; i < 8; i++){
        int e = (i * 512 + tid) * 8; int r = e >> 7, c = e & 127;
        brb[i] = *(const s16x8*)(g1t + (size_t)r * K2 + k0 + c);
      }
    };
    auto store2 = [&](){
      char* Bc = (char*)Bs;
      #pragma unroll
      for (int i = 0; i < 8; i++){
        int e = (i * 512 + tid) * 8; int r = e >> 7, c = e & 127;
        *(s16x8*)(Bc + (((r * BK + c) * 2) ^ ((r & 7) << 4))) = brb[i];
      }
    };

    f32x4 acc[2][4];
    #pragma unroll
    for (int m = 0; m < 2; m++)
      #pragma unroll
      for (int n = 0; n < 4; n++)
        acc[m][n] = (f32x4){0.f, 0.f, 0.f, 0.f};

    load2(0);
    for (int kt = 0; kt < K2 / BK; ++kt){
      __syncthreads();     // also guards H2s writes at kt=0
      store2();
      __syncthreads();
      if (kt + 1 < K2 / BK) load2((kt + 1) * BK);
      const char* Hc = (const char*)H2s;
      const char* Bc = (const char*)Bs;
      #pragma unroll
      for (int ks = 0; ks < 4; ++ks){
        s16x8 af[2], bfr[4];
        #pragma unroll
        for (int m = 0; m < 2; m++){
          int r = wr * 32 + m * 16 + (lane & 15);
          af[m] = *(const s16x8*)(Hc + (((r * 256 + kt * 128 + ks * 32 + kof) * 2) ^ ((r & 7) << 4)));
        }
        #pragma unroll
        for (int n = 0; n < 4; n++){
          int r = wc * 64 + n * 16 + (lane & 15);
          bfr[n] = *(const s16x8*)(Bc + (((r * BK + ks * 32 + kof) * 2) ^ ((r & 7) << 4)));
        }
        #pragma unroll
        for (int m = 0; m < 2; m++)
          #pragma unroll
          for (int n = 0; n < 4; n++)
            acc[m][n] = __builtin_amdgcn_mfma_f32_16x16x32_bf16(af[m], bfr[n], acc[m][n], 0, 0, 0);
      }
    }
    #pragma unroll
    for (int m = 0; m < 2; m++){
      #pragma unroll
      for (int n = 0; n < 4; n++){
        int col = wc * 64 + n * 16 + (lane & 15);
        int row0 = bm + wr * 32 + m * 16 + (lane >> 4) * 4;
        float v0 = acc[m][n][0] * dis[row0 + 0] * SC;
        float v1 = acc[m][n][1] * dis[row0 + 1] * SC;
        float v2 = acc[m][n][2] * dis[row0 + 2] * SC;
        float v3 = acc[m][n][3] * dis[row0 + 3] * SC;
        *(u32*)(tT + (size_t)col * M + row0) = pk_fp8x4(v0, v1, v2, v3);
      }
    }
  }
}

// ---------------- MX fp8 GEMM, 3-buffer counted-vmcnt pipeline ----------------
// P[z] = A8[M, kz:kz+Ksub] @ B8t[N=BN, kz:kz+Ksub]^T ; BM=128, 8 waves (2x4).
template<int BM, int BN>
__global__ __launch_bounds__(512, 1)
void gemm_mx(const unsigned char* __restrict__ A8, const unsigned char* __restrict__ B8,
             float* __restrict__ P, int M, int N, int K, int Ksub)
{
  constexpr int BK = 128;
  constexpr int AT = BM * BK;
  constexpr int BT = BN * BK;
  constexpr int AIT = AT / (512 * 16);
  constexpr int BIT = BT / (512 * 16);
  constexpr int NL = AIT + BIT;          // global_load_lds per stage (per wave)
  constexpr int WM = 2, WN = 4;
  constexpr int WTM = BM / WM;
  constexpr int WTN = BN / WN;
  constexpr int FM = WTM / 32;
  constexpr int FN = WTN / 32;
  static_assert(AIT >= 1 && BIT >= 1, "staging");

  __shared__ __align__(16) char LDS[3 * (AT + BT)];

  const int tid = threadIdx.x;
  const int lane = tid & 63;
  const int wid = tid >> 6;
  const int wr = wid >> 2;
  const int wc = wid & 3;
  const int bm = blockIdx.x * BM;
  const int kz = blockIdx.z * Ksub;

  auto stage = [&](int buf, int k0){
    char* ab = LDS + buf * (AT + BT);
    #pragma unroll
    for (int i = 0; i < AIT; i++){
      int e = (i * 512 + tid) * 16;
      int r = e >> 7, c = e & 127;
      int cc = c ^ ((r & 7) << 4);
      const unsigned char* g = A8 + (size_t)(bm + r) * K + k0 + cc;
      __builtin_amdgcn_global_load_lds((const __attribute__((address_space(1))) unsigned int*)g,
          (__attribute__((address_space(3))) unsigned int*)(ab + e), 16, 0, 0);
    }
    char* bb = ab + AT;
    #pragma unroll
    for (int i = 0; i < BIT; i++){
      int e = (i * 512 + tid) * 16;
      int r = e >> 7, c = e & 127;
      int cc = c ^ ((r & 7) << 4);
      const unsigned char* g = B8 + (size_t)r * K + k0 + cc;
      __builtin_amdgcn_global_load_lds((const __attribute__((address_space(1))) unsigned int*)g,
          (__attribute__((address_space(3))) unsigned int*)(bb + e), 16, 0, 0);
    }
  };

  f32x16 acc[FM][FN];
  #pragma unroll
  for (int m = 0; m < FM; m++)
    #pragma unroll
    for (int n = 0; n < FN; n++)
      #pragma unroll
      for (int i = 0; i < 16; i++)
        acc[m][n][i] = 0.f;

  const int nk = Ksub / BK;
  stage(0, kz);
  stage(1, kz + BK);
  for (int kt = 0; kt < nk; ++kt){
    // wait for tile kt's loads only; tile kt+1's NL loads stay in flight.
    if (kt + 1 < nk) asm volatile("s_waitcnt vmcnt(%0)" :: "n"(NL) : "memory");
    else             asm volatile("s_waitcnt vmcnt(0)" ::: "memory");
    __builtin_amdgcn_s_barrier();
    if (kt + 2 < nk) stage((kt + 2) % 3, kz + (kt + 2) * BK);
    const char* ab = LDS + (kt % 3) * (AT + BT);
    const char* bb = ab + AT;
    #pragma unroll
    for (int ks = 0; ks < 2; ks++){
      const int c0 = ks * 64 + (lane >> 5) * 32;
      i32x8 af[FM], bf_[FN];
      #pragma unroll
      for (int m = 0; m < FM; m++){
        int r = wr * WTM + m * 32 + (lane & 31);
        int sw = (r & 7) << 4;
        int o = r * BK + c0;
        u32x4 lo = *(const u32x4*)(ab + (o ^ sw));
        u32x4 hi = *(const u32x4*)(ab + ((o + 16) ^ sw));
        af[m][0] = lo[0]; af[m][1] = lo[1]; af[m][2] = lo[2]; af[m][3] = lo[3];
        af[m][4] = hi[0]; af[m][5] = hi[1]; af[m][6] = hi[2]; af[m][7] = hi[3];
      }
      #pragma unroll
      for (int n = 0; n < FN; n++){
        int r = wc * WTN + n * 32 + (lane & 31);
        int sw = (r & 7) << 4;
        int o = r * BK + c0;
        u32x4 lo = *(const u32x4*)(bb + (o ^ sw));
        u32x4 hi = *(const u32x4*)(bb + ((o + 16) ^ sw));
        bf_[n][0] = lo[0]; bf_[n][1] = lo[1]; bf_[n][2] = lo[2]; bf_[n][3] = lo[3];
        bf_[n][4] = hi[0]; bf_[n][5] = hi[1]; bf_[n][6] = hi[2]; bf_[n][7] = hi[3];
      }
      #pragma unroll
      for (int m = 0; m < FM; m++)
        #pragma unroll
        for (int n = 0; n < FN; n++)
          acc[m][n] = __builtin_amdgcn_mfma_scale_f32_32x32x64_f8f6f4(
              af[m], bf_[n], acc[m][n], 0, 0, 0, 0x7F7F7F7F, 0, 0x7F7F7F7F);
    }
  }

  float* Pz = P + (size_t)blockIdx.z * M * N;
  #pragma unroll
  for (int m = 0; m < FM; m++){
    #pragma unroll
    for (int n = 0; n < FN; n++){
      int colg = wc * WTN + n * 32 + (lane & 31);
      int rbase = bm + wr * WTM + m * 32 + (lane >> 5) * 4;
      #pragma unroll
      for (int i = 0; i < 16; i++){
        int rowg = rbase + (i & 3) + 8 * (i >> 2);
        Pz[(size_t)rowg * N + colg] = acc[m][n][i];
      }
    }
  }
}

// ---------------- fused reduce(2) + gcn2-prescale: t2T = fp8(SC*dis*(h3@g2w))^T ---------------
__global__ __launch_bounds__(256, 1)
void t2g_kernel(const float* __restrict__ part, const float* __restrict__ dis,
                const float* __restrict__ g1b, const u16* __restrict__ g2t,
                unsigned char* __restrict__ t2T)
{
  constexpr int M = 16384, H = 256, BK = 64;
  constexpr float SC = 256.f, SCI = 1.f / 256.f;
  const size_t MN = (size_t)M * H;

  __shared__ u16 As[64 * BK];
  __shared__ u16 Bs[128 * BK];

  const int tid = threadIdx.x;
  const int lane = tid & 63;
  const int wid = tid >> 6;
  const int wr = wid >> 1;
  const int wc = wid & 1;
  const int bm = blockIdx.x * 64;
  const int kof = (lane >> 4) * 8;

  f32x4 a0r[4], a1r[4], gbr[4];
  float dsr[4];
  s16x8 brb[4];

  auto load_tiles = [&](int k0){
    #pragma unroll
    for (int i = 0; i < 4; i++){
      int e = (i * 256 + tid) * 4; int r = e >> 6, c = e & 63;
      size_t pi = (size_t)(bm + r) * H + k0 + c;
      a0r[i] = *(const f32x4*)(part + pi);
      a1r[i] = *(const f32x4*)(part + MN + pi);
      gbr[i] = *(const f32x4*)(g1b + k0 + c);
      dsr[i] = dis[bm + r];
    }
    #pragma unroll
    for (int i = 0; i < 4; i++){
      int e = (i * 256 + tid) * 8; int r = e >> 6, c = e & 63;
      brb[i] = *(const s16x8*)(g2t + (size_t)r * H + k0 + c);
    }
  };
  auto store_tiles = [&](){
    char* Ac = (char*)As; char* Bc = (char*)Bs;
    #pragma unroll
    for (int i = 0; i < 4; i++){
      int e = (i * 256 + tid) * 4; int r = e >> 6, c = e & 63;
      float dsc = dsr[i] * SCI;
      s16x4 o;
      #pragma unroll
      for (int j = 0; j < 4; j++){
        float vv = fmaxf(dsc * (a0r[i][j] + a1r[i][j]) + gbr[i][j], 0.f);
        o[j] = (short)f2bf(vv);
      }
      *(s16x4*)(Ac + (((r * BK + c) * 2) ^ ((r & 7) << 4))) = o;
    }
    #pragma unroll
    for (int i = 0; i < 4; i++){
      int e = (i * 256 + tid) * 8; int r = e >> 6, c = e & 63;
      *(s16x8*)(Bc + (((r * BK + c) * 2) ^ ((r & 7) << 4))) = brb[i];
    }
  };

  f32x4 acc[2][4];
  #pragma unroll
  for (int m = 0; m < 2; m++)
    #pragma unroll
    for (int n = 0; n < 4; n++)
      acc[m][n] = (f32x4){0.f, 0.f, 0.f, 0.f};

  load_tiles(0);
  for (int kt = 0; kt < H / BK; ++kt){
    __syncthreads();
    store_tiles();
    __syncthreads();
    if (kt + 1 < H / BK) load_tiles((kt + 1) * BK);
    const char* Ac = (const char*)As;
    const char* Bc = (const char*)Bs;
    #pragma unroll
    for (int ks = 0; ks < 2; ++ks){
      s16x8 af[2], bfr[4];
      #pragma unroll
      for (int m = 0; m < 2; m++){
        int r = wr * 32 + m * 16 + (lane & 15);
        af[m] = *(const s16x8*)(Ac + (((r * BK + ks * 32 + kof) * 2) ^ ((r & 7) << 4)));
      }
      #pragma unroll
      for (int n = 0; n < 4; n++){
        int r = wc * 64 + n * 16 + (lane & 15);
        bfr[n] = *(const s16x8*)(Bc + (((r * BK + ks * 32 + kof) * 2) ^ ((r & 7) << 4)));
      }
      #pragma unroll
      for (int m = 0; m < 2; m++)
        #pragma unroll
        for (int n = 0; n < 4; n++)
          acc[m][n] = __builtin_amdgcn_mfma_f32_16x16x32_bf16(af[m], bfr[n], acc[m][n], 0, 0, 0);
    }
  }

  #pragma unroll
  for (int m = 0; m < 2; m++){
    #pragma unroll
    for (int n = 0; n < 4; n++){
      int col = wc * 64 + n * 16 + (lane & 15);
      int row0 = bm + wr * 32 + m * 16 + (lane >> 4) * 4;
      float v0 = acc[m][n][0] * dis[row0 + 0] * SC;
      float v1 = acc[m][n][1] * dis[row0 + 1] * SC;
      float v2 = acc[m][n][2] * dis[row0 + 2] * SC;
      float v3 = acc[m][n][3] * dis[row0 + 3] * SC;
      *(u32*)(t2T + (size_t)col * M + row0) = pk_fp8x4(v0, v1, v2, v3);
    }
  }
}

// ---------------- fused reduce(2) + classifier ----------------
__global__ __launch_bounds__(256) void cls2_kernel(const float* __restrict__ part,
                                                   const float* __restrict__ dis,
                                                   const float* __restrict__ g2b,
                                                   const float* __restrict__ w,
                                                   const float* __restrict__ b,
                                                   float* __restrict__ out)
{
  constexpr int M = 16384, G = 128;
  constexpr float SCI = 1.f / 256.f;
  const size_t MN = (size_t)M * G;
  __shared__ float ws_[G * 10];
  __shared__ float bs_[10];
  __shared__ float gb_[G];
  for (int i = threadIdx.x; i < G * 10; i += 256) ws_[i] = w[i];
  if (threadIdx.x < 10) bs_[threadIdx.x] = b[threadIdx.x];
  if (threadIdx.x < G) gb_[threadIdx.x] = g2b[threadIdx.x];
  __syncthreads();
  int row = blockIdx.x * 256 + threadIdx.x;
  const float* p0 = part + (size_t)row * G;
  const float* p1 = p0 + MN;
  float dr = dis[row] * SCI;
  float acc[10];
  #pragma unroll
  for (int c = 0; c < 10; c++) acc[c] = bs_[c];
  for (int k16 = 0; k16 < G; k16 += 16){
    f32x4 a0[4], a1[4];
    #pragma unroll
    for (int j = 0; j < 4; j++){
      a0[j] = *(const f32x4*)(p0 + k16 + 4 * j);
      a1[j] = *(const f32x4*)(p1 + k16 + 4 * j);
    }
    #pragma unroll
    for (int j = 0; j < 16; j++){
      float h = fmaxf(dr * (a0[j >> 2][j & 3] + a1[j >> 2][j & 3]) + gb_[k16 + j], 0.f);
      #pragma unroll
      for (int c = 0; c < 10; c++) acc[c] = fmaf(h, ws_[(k16 + j) * 10 + c], acc[c]);
    }
  }
  #pragma unroll
  for (int c = 0; c < 10; c++){
    float sg = 1.f / (1.f + expf(-acc[c]));
    sg = fminf(fmaxf(sg, 1e-10f), 1.f - 1e-10f);
    out[(size_t)row * 10 + c] = sg;
  }
}

// ---------------- launcher ----------------

extern "C" void kernel_launch(void* const* d_in, const int* in_sizes, int n_in,
                              void* d_out, int out_size, void* d_ws, size_t ws_size,
                              hipStream_t stream)
{
  (void)in_sizes; (void)n_in; (void)out_size; (void)ws_size;
  const float* feature = (const float*)d_in[0];
  const float* adj     = (const float*)d_in[1];
  const float* enc_w1  = (const float*)d_in[2];
  const float* enc_b1  = (const float*)d_in[3];
  const float* bn1_g   = (const float*)d_in[4];
  const float* bn1_b   = (const float*)d_in[5];
  const float* bn1_m   = (const float*)d_in[6];
  const float* bn1_v   = (const float*)d_in[7];
  const float* enc_w2  = (const float*)d_in[8];
  const float* enc_b2  = (const float*)d_in[9];
  const float* bn2_g   = (const float*)d_in[10];
  const float* bn2_b   = (const float*)d_in[11];
  const float* bn2_m   = (const float*)d_in[12];
  const float* bn2_v   = (const float*)d_in[13];
  const float* gcn1_w  = (const float*)d_in[14];
  const float* gcn1_b  = (const float*)d_in[15];
  const float* gcn2_w  = (const float*)d_in[16];
  const float* gcn2_b  = (const float*)d_in[17];
  const float* cls_w   = (const float*)d_in[18];
  const float* cls_b   = (const float*)d_in[19];
  float* out = (float*)d_out;

  const int NN = 16384, F = 1024, H1 = 512, E = 256, H = 256, G = 128;

  char* ws = (char*)d_ws;
  size_t off = 0;
  auto alloc = [&](size_t bytes) -> char* {
    char* p = ws + off; off += (bytes + 255) & ~(size_t)255; return p;
  };
  float* dis = (float*)alloc((size_t)NN * 4);
  float* s1  = (float*)alloc((size_t)H1 * 4);
  float* bb1 = (float*)alloc((size_t)H1 * 4);
  float* s2  = (float*)alloc((size_t)E * 4);
  float* bb2 = (float*)alloc((size_t)E * 4);
  u16* w1t = (u16*)alloc((size_t)H1 * F * 2);
  u16* w2t = (u16*)alloc((size_t)E * H1 * 2);
  u16* g1t = (u16*)alloc((size_t)H * E * 2);
  u16* g2t = (u16*)alloc((size_t)G * H * 2);
  u16* h1  = (u16*)alloc((size_t)NN * H1 * 2);
  unsigned char* tT  = (unsigned char*)alloc((size_t)E * NN);
  unsigned char* t2T = (unsigned char*)alloc((size_t)G * NN);
  float* part = (float*)alloc((size_t)2 * NN * H * 4);
  unsigned char* adj8 = (unsigned char*)alloc((size_t)NN * NN);

  // 1) w1 transpose-convert + bn1 fold
  prep0_kernel<<<514, 256, 0, stream>>>(enc_w1, w1t, bn1_g, bn1_b, bn1_m, bn1_v, enc_b1, s1, bb1);

  // 2) fused: enc1 GEMM + degree/fp8 convert + w2t/g1t/g2t/bn2 preps
  enc1_deg_kernel<<<256 + NN + 225, 256, 0, stream>>>(
      feature, w1t, h1, s1, bb1, adj, adj8, dis,
      enc_w2, w2t, gcn1_w, g1t, gcn2_w, g2t,
      bn2_g, bn2_b, bn2_m, bn2_v, enc_b2, s2, bb2);

  // 3) fused enc2 + gcn1 prescale -> tT (fp8, transposed)
  h2tT_kernel<<<NN / 64, 512, 0, stream>>>(h1, w2t, s2, bb2, g1t, dis, tT);

  // 4) part[z] = adj8 @ tT (split-K 2, MX fp8, counted-vmcnt pipeline)
  gemm_mx<128,256><<<dim3(NN/128, 1, 2), 512, 0, stream>>>(
      adj8, tT, part, NN, H, NN, NN/2);

  // 5) fused reduce(2) + gcn2 prescale -> t2T (fp8, transposed)
  t2g_kernel<<<NN / 64, 256, 0, stream>>>(part, dis, gcn1_b, g2t, t2T);

  // 6) part[z] = adj8 @ t2T (split-K 2)
  gemm_mx<128,128><<<dim3(NN/128, 1, 2), 512, 0, stream>>>(
      adj8, t2T, part, NN, G, NN, NN/2);

  // 7) fused reduce(2) + classifier
  cls2_kernel<<<NN / 256, 256, 0, stream>>>(part, dis, gcn2_b, cls_w, cls_b, out);
}